// Round 1
// baseline (591.928 us; speedup 1.0000x reference)
//
#include <hip/hip_runtime.h>
#include <math.h>

#define B_  8
#define T_  8192
#define T2_ 4096
#define F_  512
#define F2_ 256
#define K_  8

// Insert (v, vi) into sorted-descending top-K list. On ties the incumbent
// (earlier t2) stays above, matching jax.lax.top_k's lowest-index-first rule.
__device__ __forceinline__ void topk_insert(float (&a)[K_], int (&id)[K_], float v, int vi) {
    if (v <= a[K_ - 1]) return;
#pragma unroll
    for (int j = 0; j < K_; ++j) {
        bool gt = v > a[j];
        float ta = gt ? a[j] : v;
        int   ti = gt ? id[j] : vi;
        a[j]  = gt ? v  : a[j];
        id[j] = gt ? vi : id[j];
        v = ta; vi = ti;
    }
}

// Phase 1: stream x once. Write main (= (e+o)/2 interleaved twice), zero-fill
// detail, and build per-(b,f) partial top-8 candidate lists over t2 sub-chunks.
// Grid: (F2/64, S/4, B). Block: (64, 4). Each thread owns 2 adjacent f's (float2).
__global__ __launch_bounds__(256) void haar_phase1(
    const float2* __restrict__ x2, float2* __restrict__ out2,
    float* __restrict__ cand_abs, int* __restrict__ cand_idx,
    int S, int L)
{
    const int tx   = threadIdx.x;               // f2 group lane
    const int ty   = threadIdx.y;               // sub-slot
    const int f2   = blockIdx.x * 64 + tx;      // 0..255
    const int slot = blockIdx.y * 4 + ty;       // 0..S-1
    const int b    = blockIdx.z;
    const int t2_0 = slot * L;

    float a0[K_], a1[K_];
    int   i0[K_], i1[K_];
#pragma unroll
    for (int j = 0; j < K_; ++j) { a0[j] = -1.f; a1[j] = -1.f; i0[j] = 0; i1[j] = 0; }

    float2* mainOut = out2;
    float2* detOut  = out2 + (size_t)B_ * T_ * F2_;
    const size_t rowBase = (size_t)b * T_;

    for (int t = 0; t < L; ++t) {
        const int t2 = t2_0 + t;
        const size_t re = (rowBase + 2 * (size_t)t2) * F2_ + f2;  // even row
        float2 e = x2[re];
        float2 o = x2[re + F2_];
        float2 low;  low.x = (e.x + o.x) * 0.5f;  low.y = (e.y + o.y) * 0.5f;
        mainOut[re]        = low;
        mainOut[re + F2_]  = low;
        float2 z; z.x = 0.f; z.y = 0.f;
        detOut[re]         = z;
        detOut[re + F2_]   = z;
        const float h0 = fabsf(e.x - o.x);
        const float h1 = fabsf(e.y - o.y);
        topk_insert(a0, i0, h0, t2);
        topk_insert(a1, i1, h1, t2);
    }

    // candidates laid out [b][slot][entry][f]; f = 2*f2 so float2/int2 stores.
    float2* ca2 = (float2*)cand_abs;
    int2*   ci2 = (int2*)cand_idx;
    const size_t cb = ((size_t)b * S + slot) * K_;
#pragma unroll
    for (int j = 0; j < K_; ++j) {
        const size_t ci = (cb + j) * F2_ + f2;
        float2 av; av.x = a0[j]; av.y = a1[j];
        int2   iv; iv.x = i0[j]; iv.y = i1[j];
        ca2[ci] = av;
        ci2[ci] = iv;
    }
}

// Phase 2: one thread per (b,f). Merge S*8 candidates -> final top-8, reload x
// at the 8 winners for exact signed values, scatter into detail.
__global__ __launch_bounds__(256) void haar_phase2(
    const float* __restrict__ x, const float* __restrict__ cand_abs,
    const int* __restrict__ cand_idx, float* __restrict__ out, int S)
{
    const int gid = blockIdx.x * 256 + threadIdx.x;   // b*F + f
    if (gid >= B_ * F_) return;
    const int b = gid >> 9;         // /512
    const int f = gid & (F_ - 1);

    float a[K_]; int id[K_];
#pragma unroll
    for (int j = 0; j < K_; ++j) { a[j] = -1.f; id[j] = 0; }

    const int n = S * K_;
    const float* ca = cand_abs + (size_t)b * S * K_ * F_ + f;
    const int*   ci = cand_idx + (size_t)b * S * K_ * F_ + f;
    for (int e = 0; e < n; ++e) {
        const float v  = ca[(size_t)e * F_];
        const int   vi = ci[(size_t)e * F_];
        topk_insert(a, id, v, vi);
    }

    float* det = out + (size_t)B_ * T_ * F_;
#pragma unroll
    for (int j = 0; j < K_; ++j) {
        const int t2 = id[j];
        const size_t re = ((size_t)b * T_ + 2 * (size_t)t2) * F_ + f;
        const float e = x[re];
        const float o = x[re + F_];
        const float val = (e - o) * 0.5f;
        det[re]      = val;
        det[re + F_] = -val;
    }
}

extern "C" void kernel_launch(void* const* d_in, const int* in_sizes, int n_in,
                              void* d_out, int out_size, void* d_ws, size_t ws_size,
                              hipStream_t stream) {
    const float* x = (const float*)d_in[0];
    float* out = (float*)d_out;

    // Choose slot count S by workspace budget: bytes = B*F*S*K*(4+4).
    int S = 64;
    while (S > 4 && (size_t)B_ * F_ * (size_t)S * K_ * 8 > ws_size) S >>= 1;
    const int L = T2_ / S;

    float* cand_abs = (float*)d_ws;
    int*   cand_idx = (int*)((char*)d_ws + (size_t)B_ * F_ * (size_t)S * K_ * 4);

    dim3 gA(F2_ / 64, S / 4, B_);
    dim3 bA(64, 4, 1);
    hipLaunchKernelGGL(haar_phase1, gA, bA, 0, stream,
                       (const float2*)x, (float2*)out, cand_abs, cand_idx, S, L);

    const int nb = (B_ * F_ + 255) / 256;
    hipLaunchKernelGGL(haar_phase2, dim3(nb), dim3(256), 0, stream,
                       x, cand_abs, cand_idx, out, S);
}

// Round 3
// 416.307 us; speedup vs baseline: 1.4219x; 1.4219x over previous
//
#include <hip/hip_runtime.h>
#include <math.h>

#define B_  8
#define T_  8192
#define T2_ 4096
#define F_  512
#define F4_ 128
#define K_  8

typedef unsigned long long u64;
typedef float fvec4 __attribute__((ext_vector_type(4)));   // native vec: ok for nontemporal builtins

// Sorted-descending top-8 insert of packed key (abs_bits<<32)|~t2.
// Keys unique (t2 unique); ~t2 gives lower-index-first on equal abs,
// matching jax.lax.top_k.
__device__ __forceinline__ void ins8(u64 (&a)[K_], u64 k) {
    if (k <= a[K_ - 1]) return;
#pragma unroll
    for (int j = 0; j < K_; ++j) {
        u64 hi = (k > a[j]) ? k : a[j];
        u64 lo = (k > a[j]) ? a[j] : k;
        a[j] = hi;
        k = lo;
    }
}

// Phase 1: stream x once (float4 lanes over f). Write main twice-interleaved,
// zero-fill detail (nontemporal: 512 MB streamed once, keep L3 for x), and
// emit per-(col,slot) top-8 candidate keys to cand[col][slot][entry].
__global__ __launch_bounds__(256) void haar_phase1(
    const fvec4* __restrict__ x4, fvec4* __restrict__ out4,
    u64* __restrict__ cand, int S, int L)
{
    const int tx   = threadIdx.x;
    const int f4   = blockIdx.x * 64 + tx;            // 0..127
    const int slot = blockIdx.y * 4 + threadIdx.y;    // 0..S-1
    const int b    = blockIdx.z;
    const int t2_0 = slot * L;

    u64 a0[K_], a1[K_], a2[K_], a3[K_];
#pragma unroll
    for (int j = 0; j < K_; ++j) { a0[j] = 0; a1[j] = 0; a2[j] = 0; a3[j] = 0; }

    fvec4* mainOut = out4;
    fvec4* detOut  = out4 + (size_t)B_ * T_ * F4_;
    const size_t rowBase = (size_t)b * T_;
    const fvec4 z = {0.f, 0.f, 0.f, 0.f};

    for (int t = 0; t < L; ++t) {
        const int t2 = t2_0 + t;
        const size_t re = (rowBase + 2 * (size_t)t2) * F4_ + f4;  // even row
        fvec4 e = x4[re];
        fvec4 o = x4[re + F4_];
        fvec4 low = (e + o) * 0.5f;
        __builtin_nontemporal_store(low, &mainOut[re]);
        __builtin_nontemporal_store(low, &mainOut[re + F4_]);
        __builtin_nontemporal_store(z,   &detOut[re]);
        __builtin_nontemporal_store(z,   &detOut[re + F4_]);
        const u64 it = (u64)(unsigned)(~t2);
        ins8(a0, ((u64)__float_as_uint(fabsf(e.x - o.x)) << 32) | it);
        ins8(a1, ((u64)__float_as_uint(fabsf(e.y - o.y)) << 32) | it);
        ins8(a2, ((u64)__float_as_uint(fabsf(e.z - o.z)) << 32) | it);
        ins8(a3, ((u64)__float_as_uint(fabsf(e.w - o.w)) << 32) | it);
    }

    // cand layout: (col * S + slot) * 8 + j, col = b*F + f. 64B per (col,slot).
    const size_t colBase = (size_t)b * F_ + 4 * (size_t)f4;
    u64* d0 = cand + ((colBase + 0) * S + slot) * K_;
    u64* d1 = cand + ((colBase + 1) * S + slot) * K_;
    u64* d2 = cand + ((colBase + 2) * S + slot) * K_;
    u64* d3 = cand + ((colBase + 3) * S + slot) * K_;
#pragma unroll
    for (int j = 0; j < K_; ++j) { d0[j] = a0[j]; d1[j] = a1[j]; d2[j] = a2[j]; d3[j] = a3[j]; }
}

// Phase 2: one wave per column. Coalesced candidate reads, per-lane top-8,
// 8 rounds of wave-wide u64 argmax, then lanes 0..7 scatter the winners.
__global__ __launch_bounds__(256) void haar_phase2(
    const float* __restrict__ x, const u64* __restrict__ cand,
    float* __restrict__ out, int S)
{
    const int lane = threadIdx.x & 63;
    const int wv   = threadIdx.x >> 6;
    const int col  = blockIdx.x * 4 + wv;      // b*F + f
    const int b    = col >> 9;
    const int f    = col & (F_ - 1);
    const int n    = S * K_;                   // candidates per column

    const u64* c = cand + (size_t)col * n;
    u64 a[K_];
#pragma unroll
    for (int j = 0; j < K_; ++j) a[j] = 0;
    for (int e = lane; e < n; e += 64) ins8(a, c[e]);

    u64 wkey = 0;
#pragma unroll
    for (int j = 0; j < K_; ++j) {
        u64 m = a[0];
#pragma unroll
        for (int s = 32; s > 0; s >>= 1) {
            u64 t = __shfl_xor(m, s, 64);
            m = (t > m) ? t : m;
        }
        if (a[0] == m) {            // exactly one lane (keys unique)
#pragma unroll
            for (int q = 0; q < K_ - 1; ++q) a[q] = a[q + 1];
            a[K_ - 1] = 0;
        }
        if (lane == j) wkey = m;
    }

    float* det = out + (size_t)B_ * T_ * F_;
    if (lane < K_) {
        const int t2 = (int)(~(unsigned)wkey);
        const size_t re = ((size_t)b * T_ + 2 * (size_t)t2) * F_ + f;
        const float e = x[re];
        const float o = x[re + F_];
        const float v = (e - o) * 0.5f;
        det[re]      = v;
        det[re + F_] = -v;
    }
}

extern "C" void kernel_launch(void* const* d_in, const int* in_sizes, int n_in,
                              void* d_out, int out_size, void* d_ws, size_t ws_size,
                              hipStream_t stream) {
    const float* x = (const float*)d_in[0];
    float* out = (float*)d_out;

    // Workspace: B*F*S*K u64 keys. Prefer S=256 (more phase-1 blocks).
    int S = 256;
    while (S > 64 && (size_t)B_ * F_ * (size_t)S * K_ * sizeof(u64) > ws_size) S >>= 1;
    const int L = T2_ / S;
    u64* cand = (u64*)d_ws;

    dim3 gA(F4_ / 64, S / 4, B_);
    dim3 bA(64, 4, 1);
    hipLaunchKernelGGL(haar_phase1, gA, bA, 0, stream,
                       (const fvec4*)x, (fvec4*)out, cand, S, L);

    const int nb = (B_ * F_) / 4;   // one wave per column, 4 waves/block
    hipLaunchKernelGGL(haar_phase2, dim3(nb), dim3(256), 0, stream,
                       x, cand, out, S);
}